// Round 12
// baseline (5388682.422 us; speedup 1.0000x reference)
//
#include <hip/hip_runtime.h>
#include <hip/hip_bf16.h>
#include <stdint.h>

#define N_W 96
#define NAG 192                      // total agents
#define NP1 97
#define W_ELEMS (N_W * NP1 * NP1)    // 903264 (divisible by 4)
#define R_ELEMS (NAG * NAG)          // 36864
#define WB ((W_ELEMS / 4 + 255) / 256)   // 883
#define RB ((R_ELEMS / 4 + 255) / 256)   // 36

// Decode one-hot tensors into packed index form.
__global__ __launch_bounds__(256) void decode_kernel(
    const float* __restrict__ W, const float* __restrict__ F,
    const float* __restrict__ R,
    short* __restrict__ ps, short* __restrict__ ord) {
    int b = blockIdx.x;
    if (b < 2 * WB) {
        const float* src = (b < WB) ? W : F;
        int abase = (b < WB) ? 0 : N_W;
        int i4 = (b - ((b < WB) ? 0 : WB)) * 256 + threadIdx.x;
        if (i4 < W_ELEMS / 4) {
            float4 v = ((const float4*)src)[i4];
            int base = i4 * 4;
            #pragma unroll
            for (int u = 0; u < 4; ++u) {
                float x = (u == 0) ? v.x : (u == 1) ? v.y : (u == 2) ? v.z : v.w;
                if (x > 0.5f) {
                    int idx = base + u;
                    int a = idx / (NP1 * NP1);
                    int rem = idx - a * (NP1 * NP1);
                    int j = rem / NP1;
                    int k = rem - j * NP1;
                    int slot = (k < 64) ? (2 * k) : (2 * (k - 64) + 1);
                    ps[(abase + a) * 128 + slot] = (short)j;
                }
            }
        }
    } else {
        int i4 = (b - 2 * WB) * 256 + threadIdx.x;
        if (i4 < R_ELEMS / 4) {
            float4 v = ((const float4*)R)[i4];
            int base = i4 * 4;
            #pragma unroll
            for (int u = 0; u < 4; ++u) {
                float x = (u == 0) ? v.x : (u == 1) ? v.y : (u == 2) ? v.z : v.w;
                if (x > 0.5f) {
                    int idx = base + u;
                    int a = idx / NAG;
                    int r = idx - a * NAG;
                    ord[r] = (short)a;
                }
            }
        }
    }
}

// Clock ruler: 24,000 DEPENDENT s_add_i32 (+ ~4.5k loop overhead).
// dur_us of this dispatch reads the effective SALU clock:
// ~12 us @ 2.4 GHz, ~36 us @ 800 MHz.
__global__ __launch_bounds__(64) void clock_probe(int* outp) {
    int x = __builtin_amdgcn_readfirstlane((int)threadIdx.x);  // born uniform -> SGPR
    #pragma clang loop unroll(disable)
    for (int i = 0; i < 1500; ++i) {
        asm volatile(
            "s_add_i32 %0, %0, 1\n"
            "s_add_i32 %0, %0, 1\n"
            "s_add_i32 %0, %0, 1\n"
            "s_add_i32 %0, %0, 1\n"
            "s_add_i32 %0, %0, 1\n"
            "s_add_i32 %0, %0, 1\n"
            "s_add_i32 %0, %0, 1\n"
            "s_add_i32 %0, %0, 1\n"
            "s_add_i32 %0, %0, 1\n"
            "s_add_i32 %0, %0, 1\n"
            "s_add_i32 %0, %0, 1\n"
            "s_add_i32 %0, %0, 1\n"
            "s_add_i32 %0, %0, 1\n"
            "s_add_i32 %0, %0, 1\n"
            "s_add_i32 %0, %0, 1\n"
            "s_add_i32 %0, %0, 1\n"
            : "+s"(x));
    }
    if (threadIdx.x == 0) outp[0] = x;
}

// Single-block sequential serial dictatorship.
// Straight-line round body: ONE branch (alive), SALU cselect routing,
// rare rank>=64 path computed always (parallel VALU, no branch).
__global__ __launch_bounds__(256, 1) void sd_kernel(
    const uint32_t* __restrict__ pk_g, const short* __restrict__ ord_g,
    float* __restrict__ out) {
    __shared__ __align__(16) uint32_t s_pko[NAG * 64 + 64];  // +64: prefetch pad
    __shared__ uint32_t s_match[NAG];

    const int t = threadIdx.x;
    const unsigned short* og = (const unsigned short*)ord_g;

    for (int idx = t; idx < NAG * 16; idx += 256) {
        int r = idx >> 4, q = idx & 15;
        int a = (int)og[r];
        ((uint4*)s_pko)[idx] = ((const uint4*)(pk_g + (a << 6)))[q];
    }
    __syncthreads();

    if (t < 64) {
        uint32_t ov0 = og[t], ov1 = og[64 + t], ov2 = og[128 + t];
        uint64_t rW = 0, rWh = 0, rF = 0, rFh = 0;   // removal masks (uniform -> SGPR)
        uint32_t c0 = 0xFFFFFFFFu, c1 = 0xFFFFFFFFu, c2 = 0xFFFFFFFFu;
        uint32_t Pc = s_pko[t];
        // per-lane slot descriptors for the CURRENT round
        uint32_t j1 = Pc & 0xFFFFu, j2 = Pc >> 16;
        uint32_t lo1 = (j1 < 64u) ? 1u : 0u, hi1 = (j1 >= 64u && j1 < 96u) ? 1u : 0u;
        uint32_t lo2 = (j2 < 64u) ? 1u : 0u, hi2 = (j2 >= 64u && j2 < 96u) ? 1u : 0u;

        auto SEG = [&](uint32_t ordv, uint32_t& cv, int segbase) {
            #pragma clang loop unroll(disable)
            for (int rr = 0; rr < 64; ++rr) {
                const int r = segbase + rr;
                uint32_t Pn = s_pko[((r + 1) << 6) + t];        // depth-1 prefetch
                int a = __builtin_amdgcn_readlane((int)ordv, rr);
                // uniform scalars (SALU)
                uint32_t isW = (a < 96) ? 1u : 0u;
                uint32_t aa = isW ? (uint32_t)a : (uint32_t)(a - 96);
                uint32_t ah = aa >> 6;
                uint64_t sb = 1ull << (aa & 63u);
                uint64_t ownw = isW ? (ah ? rWh : rW) : (ah ? rFh : rF);
                uint32_t alive = ((uint32_t)(~ownw >> (aa & 63u))) & 1u;
                uint64_t s_lo = ah ? 0ull : sb, s_hi = ah ? sb : 0ull;
                uint64_t olo = isW ? rF : rW, ohi = isW ? rFh : rWh;
                uint64_t chl = 0ull, chh = 0ull;
                uint32_t cellu = 0xFFFFFFFFu;
                if (alive) {
                    // per-lane availability test; both slots, no branch
                    uint32_t b1 = (((uint32_t)(olo >> (j1 & 63u))) & lo1)
                                | (((uint32_t)(ohi >> (j1 & 63u))) & hi1);
                    uint32_t b2 = (((uint32_t)(olo >> (j2 & 63u))) & lo2)
                                | (((uint32_t)(ohi >> (j2 & 63u))) & hi2);
                    unsigned long long m1 = __ballot(b1 == 0u);
                    unsigned long long m2 = __ballot(b2 == 0u) & 0x1FFFFFFFFull;
                    int e1 = __ffsll(m1) - 1;
                    int e2 = 63 + __ffsll(m2);
                    int k = (m1 != 0ull) ? e1 : e2;
                    uint32_t pc = (uint32_t)__builtin_amdgcn_readlane((int)Pc, k & 63);
                    uint32_t js = (k >= 64) ? (pc >> 16) : (pc & 0xFFFFu);
                    uint32_t tk = (js < 96u) ? 1u : 0u;
                    uint64_t cb = 1ull << (js & 63u);
                    uint32_t jh = js >> 6;
                    chl = (tk && !jh) ? cb : 0ull;
                    chh = (tk && jh) ? cb : 0ull;
                    cellu = isW ? (aa * (uint32_t)NP1 + js) : (js * (uint32_t)NP1 + aa);
                }
                // route updates (SALU cselect + or), self->own side, choice->opponent
                rW  |= isW ? s_lo : chl;   rWh |= isW ? s_hi : chh;
                rF  |= isW ? chl : s_lo;   rFh |= isW ? chh : s_hi;
                // lane-capture (2 VALU, off-chain)
                cv = (t == (uint32_t)rr) ? cellu : cv;
                // advance per-lane descriptors (off-chain)
                Pc = Pn;
                j1 = Pn & 0xFFFFu; j2 = Pn >> 16;
                lo1 = (j1 < 64u) ? 1u : 0u; hi1 = (j1 >= 64u && j1 < 96u) ? 1u : 0u;
                lo2 = (j2 < 64u) ? 1u : 0u; hi2 = (j2 >= 64u && j2 < 96u) ? 1u : 0u;
            }
        };
        SEG(ov0, c0, 0);
        SEG(ov1, c1, 64);
        SEG(ov2, c2, 128);
        s_match[t] = c0; s_match[64 + t] = c1; s_match[128 + t] = c2;
    } else {
        for (int i = t - 64; i < 2352; i += 192)
            ((float4*)out)[i] = make_float4(0.f, 0.f, 0.f, 0.f);
        if (t == 64) out[9408] = 0.f;
    }
    __syncthreads();
    if (t < NAG) {
        uint32_t c = s_match[t];
        if (c != 0xFFFFFFFFu) out[c] = 1.0f;
    }
}

extern "C" void kernel_launch(void* const* d_in, const int* in_sizes, int n_in,
                              void* d_out, int out_size, void* d_ws, size_t ws_size,
                              hipStream_t stream) {
    const float* W = (const float*)d_in[0];
    const float* F = (const float*)d_in[1];
    const float* R = (const float*)d_in[2];
    float* out = (float*)d_out;

    uint32_t* packed = (uint32_t*)d_ws;                 // NAG*64 u32 = 48 KiB
    short* ord = (short*)((char*)d_ws + NAG * 64 * 4);  // 192 shorts
    int* probe_out = (int*)((char*)d_ws + (64 << 10));

    decode_kernel<<<2 * WB + RB, 256, 0, stream>>>(W, F, R, (short*)packed, ord);
    clock_probe<<<1, 64, 0, stream>>>(probe_out);       // clock ruler (one-time cost)
    sd_kernel<<<1, 256, 0, stream>>>(packed, ord, out);
}

// Round 13
// 152.711 us; speedup vs baseline: 35286.7932x; 35286.7932x over previous
//
#include <hip/hip_runtime.h>
#include <hip/hip_bf16.h>
#include <stdint.h>

#define N_W 96
#define NAG 192                      // total agents
#define NP1 97
#define W_ELEMS (N_W * NP1 * NP1)    // 903264 (divisible by 4)
#define R_ELEMS (NAG * NAG)          // 36864
#define WB ((W_ELEMS / 4 + 255) / 256)   // 883
#define RB ((R_ELEMS / 4 + 255) / 256)   // 36

// Decode one-hot tensors into packed index form.
__global__ __launch_bounds__(256) void decode_kernel(
    const float* __restrict__ W, const float* __restrict__ F,
    const float* __restrict__ R,
    short* __restrict__ ps, short* __restrict__ ord) {
    int b = blockIdx.x;
    if (b < 2 * WB) {
        const float* src = (b < WB) ? W : F;
        int abase = (b < WB) ? 0 : N_W;
        int i4 = (b - ((b < WB) ? 0 : WB)) * 256 + threadIdx.x;
        if (i4 < W_ELEMS / 4) {
            float4 v = ((const float4*)src)[i4];
            int base = i4 * 4;
            #pragma unroll
            for (int u = 0; u < 4; ++u) {
                float x = (u == 0) ? v.x : (u == 1) ? v.y : (u == 2) ? v.z : v.w;
                if (x > 0.5f) {
                    int idx = base + u;
                    int a = idx / (NP1 * NP1);
                    int rem = idx - a * (NP1 * NP1);
                    int j = rem / NP1;
                    int k = rem - j * NP1;
                    int slot = (k < 64) ? (2 * k) : (2 * (k - 64) + 1);
                    ps[(abase + a) * 128 + slot] = (short)j;
                }
            }
        }
    } else {
        int i4 = (b - 2 * WB) * 256 + threadIdx.x;
        if (i4 < R_ELEMS / 4) {
            float4 v = ((const float4*)R)[i4];
            int base = i4 * 4;
            #pragma unroll
            for (int u = 0; u < 4; ++u) {
                float x = (u == 0) ? v.x : (u == 1) ? v.y : (u == 2) ? v.z : v.w;
                if (x > 0.5f) {
                    int idx = base + u;
                    int a = idx / NAG;
                    int r = idx - a * NAG;
                    ord[r] = (short)a;
                }
            }
        }
    }
}

// Clock ruler: 24,000 dependent s_mov_b32 (latency 1, NO SCC write) + ~4.5k
// loop overhead ≈ 28.5k SALU cycles. dur_us reads the effective SALU clock:
// ~12 us @ 2.4 GHz, ~47 us @ 600 MHz.
__global__ __launch_bounds__(64) void clock_probe(int* outp) {
    int x = __builtin_amdgcn_readfirstlane((int)threadIdx.x);  // born uniform -> SGPR
    #pragma clang loop unroll(disable)
    for (int i = 0; i < 1500; ++i) {
        asm volatile(
            "s_mov_b32 %0, %0\n"
            "s_mov_b32 %0, %0\n"
            "s_mov_b32 %0, %0\n"
            "s_mov_b32 %0, %0\n"
            "s_mov_b32 %0, %0\n"
            "s_mov_b32 %0, %0\n"
            "s_mov_b32 %0, %0\n"
            "s_mov_b32 %0, %0\n"
            "s_mov_b32 %0, %0\n"
            "s_mov_b32 %0, %0\n"
            "s_mov_b32 %0, %0\n"
            "s_mov_b32 %0, %0\n"
            "s_mov_b32 %0, %0\n"
            "s_mov_b32 %0, %0\n"
            "s_mov_b32 %0, %0\n"
            "s_mov_b32 %0, %0\n"
            : "+s"(x));
    }
    if (threadIdx.x == 0) outp[0] = x;
}

// Single-block sequential serial dictatorship.
// Straight-line round body: ONE branch (alive), SALU cselect routing,
// rare rank>=64 path computed always (parallel VALU, no branch).
__global__ __launch_bounds__(256, 1) void sd_kernel(
    const uint32_t* __restrict__ pk_g, const short* __restrict__ ord_g,
    float* __restrict__ out) {
    __shared__ __align__(16) uint32_t s_pko[NAG * 64 + 64];  // +64: prefetch pad
    __shared__ uint32_t s_match[NAG];

    const int t = threadIdx.x;
    const unsigned short* og = (const unsigned short*)ord_g;

    for (int idx = t; idx < NAG * 16; idx += 256) {
        int r = idx >> 4, q = idx & 15;
        int a = (int)og[r];
        ((uint4*)s_pko)[idx] = ((const uint4*)(pk_g + (a << 6)))[q];
    }
    __syncthreads();

    if (t < 64) {
        uint32_t ov0 = og[t], ov1 = og[64 + t], ov2 = og[128 + t];
        uint64_t rW = 0, rWh = 0, rF = 0, rFh = 0;   // removal masks (uniform -> SGPR)
        uint32_t c0 = 0xFFFFFFFFu, c1 = 0xFFFFFFFFu, c2 = 0xFFFFFFFFu;
        uint32_t Pc = s_pko[t];
        uint32_t j1 = Pc & 0xFFFFu, j2 = Pc >> 16;
        uint32_t lo1 = (j1 < 64u) ? 1u : 0u, hi1 = (j1 >= 64u && j1 < 96u) ? 1u : 0u;
        uint32_t lo2 = (j2 < 64u) ? 1u : 0u, hi2 = (j2 >= 64u && j2 < 96u) ? 1u : 0u;

        auto SEG = [&](uint32_t ordv, uint32_t& cv, int segbase) {
            #pragma clang loop unroll(disable)
            for (int rr = 0; rr < 64; ++rr) {
                const int r = segbase + rr;
                uint32_t Pn = s_pko[((r + 1) << 6) + t];        // depth-1 prefetch
                int a = __builtin_amdgcn_readlane((int)ordv, rr);
                uint32_t isW = (a < 96) ? 1u : 0u;
                uint32_t aa = isW ? (uint32_t)a : (uint32_t)(a - 96);
                uint32_t ah = aa >> 6;
                uint64_t sb = 1ull << (aa & 63u);
                uint64_t ownw = isW ? (ah ? rWh : rW) : (ah ? rFh : rF);
                uint32_t alive = ((uint32_t)(~ownw >> (aa & 63u))) & 1u;
                uint64_t s_lo = ah ? 0ull : sb, s_hi = ah ? sb : 0ull;
                uint64_t olo = isW ? rF : rW, ohi = isW ? rFh : rWh;
                uint64_t chl = 0ull, chh = 0ull;
                uint32_t cellu = 0xFFFFFFFFu;
                if (alive) {
                    uint32_t b1 = (((uint32_t)(olo >> (j1 & 63u))) & lo1)
                                | (((uint32_t)(ohi >> (j1 & 63u))) & hi1);
                    uint32_t b2 = (((uint32_t)(olo >> (j2 & 63u))) & lo2)
                                | (((uint32_t)(ohi >> (j2 & 63u))) & hi2);
                    unsigned long long m1 = __ballot(b1 == 0u);
                    unsigned long long m2 = __ballot(b2 == 0u) & 0x1FFFFFFFFull;
                    int e1 = __ffsll(m1) - 1;
                    int e2 = 63 + __ffsll(m2);
                    int k = (m1 != 0ull) ? e1 : e2;
                    uint32_t pc = (uint32_t)__builtin_amdgcn_readlane((int)Pc, k & 63);
                    uint32_t js = (k >= 64) ? (pc >> 16) : (pc & 0xFFFFu);
                    uint32_t tk = (js < 96u) ? 1u : 0u;
                    uint64_t cb = 1ull << (js & 63u);
                    uint32_t jh = js >> 6;
                    chl = (tk && !jh) ? cb : 0ull;
                    chh = (tk && jh) ? cb : 0ull;
                    cellu = isW ? (aa * (uint32_t)NP1 + js) : (js * (uint32_t)NP1 + aa);
                }
                rW  |= isW ? s_lo : chl;   rWh |= isW ? s_hi : chh;
                rF  |= isW ? chl : s_lo;   rFh |= isW ? chh : s_hi;
                cv = (t == (uint32_t)rr) ? cellu : cv;
                Pc = Pn;
                j1 = Pn & 0xFFFFu; j2 = Pn >> 16;
                lo1 = (j1 < 64u) ? 1u : 0u; hi1 = (j1 >= 64u && j1 < 96u) ? 1u : 0u;
                lo2 = (j2 < 64u) ? 1u : 0u; hi2 = (j2 >= 64u && j2 < 96u) ? 1u : 0u;
            }
        };
        SEG(ov0, c0, 0);
        SEG(ov1, c1, 64);
        SEG(ov2, c2, 128);
        s_match[t] = c0; s_match[64 + t] = c1; s_match[128 + t] = c2;
    } else {
        for (int i = t - 64; i < 2352; i += 192)
            ((float4*)out)[i] = make_float4(0.f, 0.f, 0.f, 0.f);
        if (t == 64) out[9408] = 0.f;
    }
    __syncthreads();
    if (t < NAG) {
        uint32_t c = s_match[t];
        if (c != 0xFFFFFFFFu) out[c] = 1.0f;
    }
}

extern "C" void kernel_launch(void* const* d_in, const int* in_sizes, int n_in,
                              void* d_out, int out_size, void* d_ws, size_t ws_size,
                              hipStream_t stream) {
    const float* W = (const float*)d_in[0];
    const float* F = (const float*)d_in[1];
    const float* R = (const float*)d_in[2];
    float* out = (float*)d_out;

    uint32_t* packed = (uint32_t*)d_ws;                 // NAG*64 u32 = 48 KiB
    short* ord = (short*)((char*)d_ws + NAG * 64 * 4);  // 192 shorts
    int* probe_out = (int*)((char*)d_ws + (64 << 10));

    clock_probe<<<1, 64, 0, stream>>>(probe_out);       // clock ruler (one-time cost)
    decode_kernel<<<2 * WB + RB, 256, 0, stream>>>(W, F, R, (short*)packed, ord);
    sd_kernel<<<1, 256, 0, stream>>>(packed, ord, out);
}

// Round 14
// 46.885 us; speedup vs baseline: 114933.2840x; 3.2571x over previous
//
#include <hip/hip_runtime.h>
#include <hip/hip_bf16.h>
#include <stdint.h>

#define N_W 96
#define NAG 192                      // total agents
#define NP1 97
#define W_ELEMS (N_W * NP1 * NP1)    // 903264 (divisible by 4)
#define R_ELEMS (NAG * NAG)          // 36864
#define WB ((W_ELEMS / 4 + 255) / 256)   // 883
#define RB ((R_ELEMS / 4 + 255) / 256)   // 36

// Decode one-hot tensors into packed index form + dictation times.
// packed word [a*64 + s] = pref[a][s] | (pref[a][s+64] << 16)
// ord[r] = dictating agent in round r; td[a] = round when agent a dictates.
__global__ __launch_bounds__(256) void decode_kernel(
    const float* __restrict__ W, const float* __restrict__ F,
    const float* __restrict__ R,
    short* __restrict__ ps, short* __restrict__ ord, short* __restrict__ td) {
    int b = blockIdx.x;
    if (b < 2 * WB) {
        const float* src = (b < WB) ? W : F;
        int abase = (b < WB) ? 0 : N_W;
        int i4 = (b - ((b < WB) ? 0 : WB)) * 256 + threadIdx.x;
        if (i4 < W_ELEMS / 4) {
            float4 v = ((const float4*)src)[i4];
            int base = i4 * 4;
            #pragma unroll
            for (int u = 0; u < 4; ++u) {
                float x = (u == 0) ? v.x : (u == 1) ? v.y : (u == 2) ? v.z : v.w;
                if (x > 0.5f) {
                    int idx = base + u;
                    int a = idx / (NP1 * NP1);
                    int rem = idx - a * (NP1 * NP1);
                    int j = rem / NP1;          // option (or 96=unmatch)
                    int k = rem - j * NP1;      // rank
                    int slot = (k < 64) ? (2 * k) : (2 * (k - 64) + 1);
                    ps[(abase + a) * 128 + slot] = (short)j;
                }
            }
        }
    } else {
        int i4 = (b - 2 * WB) * 256 + threadIdx.x;
        if (i4 < R_ELEMS / 4) {
            float4 v = ((const float4*)R)[i4];
            int base = i4 * 4;
            #pragma unroll
            for (int u = 0; u < 4; ++u) {
                float x = (u == 0) ? v.x : (u == 1) ? v.y : (u == 2) ? v.z : v.w;
                if (x > 0.5f) {
                    int idx = base + u;
                    int a = idx / NAG;
                    int r = idx - a * NAG;
                    ord[r] = (short)a;
                    td[a] = (short)r;
                }
            }
        }
    }
}

// Single-block sequential serial dictatorship.
// Lone-wave issue cadence ~4.7cyc/instr => minimize serial instruction count:
// static (dictation-time) removals BAKED into staged prefs (sentinel 97);
// runtime masks track chosen-only. Branchy body, cold slot-2 path.
__global__ __launch_bounds__(256, 1) void sd_kernel(
    const uint32_t* __restrict__ pk_g, const short* __restrict__ ord_g,
    const short* __restrict__ td_g, float* __restrict__ out) {
    __shared__ __align__(16) uint32_t s_pko[NAG * 64 + 64];  // +64: prefetch pad
    __shared__ uint32_t s_match[NAG];
    __shared__ unsigned short s_og[NAG];
    __shared__ unsigned short s_td[NAG];

    const int t = threadIdx.x;
    if (t < NAG) {
        s_og[t] = ((const unsigned short*)ord_g)[t];
        s_td[t] = ((const unsigned short*)td_g)[t];
    }
    __syncthreads();

    // staging: s_pko[r][lane] = baked pk[ord[r]][lane]
    // bake: pref j -> 97 (always-unavailable sentinel) if its owner dictates
    // before round r. unmatch (96) and garbage (>=2^7) slots left untouched.
    for (int idx = t; idx < NAG * 16; idx += 256) {
        int r = idx >> 4, q = idx & 15;
        int a = (int)s_og[r];
        uint4 w = ((const uint4*)(pk_g + (a << 6)))[q];
        int opp = (a < 96) ? 96 : 0;
        uint32_t* pw = (uint32_t*)&w;
        #pragma unroll
        for (int u = 0; u < 4; ++u) {
            uint32_t x = pw[u];
            uint32_t j1 = x & 0xFFFFu, j2 = x >> 16;
            if (j1 < 96u && (int)s_td[opp + j1] < r) j1 = 97u;
            if (j2 < 96u && (int)s_td[opp + j2] < r) j2 = 97u;
            pw[u] = j1 | (j2 << 16);
        }
        ((uint4*)s_pko)[idx] = w;
    }
    __syncthreads();

    if (t < 64) {
        uint32_t ov0 = s_og[t], ov1 = s_og[64 + t], ov2 = s_og[128 + t];
        // chosen masks only (bit33 = sentinel-97, permanently unavailable)
        uint64_t chW = 0, chWh = (1ull << 33), chF = 0, chFh = (1ull << 33);
        uint32_t c0 = 0xFFFFFFFFu, c1 = 0xFFFFFFFFu, c2 = 0xFFFFFFFFu;
        uint32_t Pc = s_pko[t];
        uint32_t j1 = Pc & 0xFFFFu;

        auto SEG = [&](uint32_t ordv, uint32_t& cv, int segbase) {
            #pragma clang loop unroll(disable)
            for (int rr = 0; rr < 64; ++rr) {
                const int r = segbase + rr;
                uint32_t Pn = s_pko[((r + 1) << 6) + t];      // depth-1 prefetch
                int a = __builtin_amdgcn_readlane((int)ordv, rr);
                if (a < 96) {                                  // worker dictates
                    uint64_t own = (a < 64) ? chW : chWh;
                    if (((own >> (a & 63)) & 1ull) == 0ull) {  // alive
                        uint32_t t0 = (uint32_t)(chF >> (j1 & 63u));
                        uint32_t t1 = (uint32_t)(chFh >> (j1 & 63u));
                        uint32_t bit = (j1 < 64u) ? t0 : t1;
                        unsigned long long m1 = __ballot((bit & 1u) == 0u);
                        uint32_t js;
                        if (m1 != 0ull) {
                            int k = __ffsll(m1) - 1;
                            js = ((uint32_t)__builtin_amdgcn_readlane((int)Pc, k)) & 0xFFFFu;
                        } else {                               // cold: rank>=64
                            uint32_t j2 = Pc >> 16;
                            uint32_t u0 = (uint32_t)(chF >> (j2 & 63u));
                            uint32_t u1 = (uint32_t)(chFh >> (j2 & 63u));
                            uint32_t b2 = (j2 < 64u) ? u0 : u1;
                            unsigned long long m2 = __ballot((b2 & 1u) == 0u) & 0x1FFFFFFFFull;
                            int k = __ffsll(m2) - 1;
                            js = ((uint32_t)__builtin_amdgcn_readlane((int)Pc, k)) >> 16;
                        }
                        if (js < 96u) {
                            if (js < 64u) chF |= 1ull << js; else chFh |= 1ull << (js & 63u);
                        }
                        uint32_t cell = (uint32_t)(a * NP1) + js;
                        cv = (t == (uint32_t)rr) ? cell : cv;  // lane-capture
                    }
                } else {                                       // firm dictates
                    int aa = a - 96;
                    uint64_t own = (aa < 64) ? chF : chFh;
                    if (((own >> (aa & 63)) & 1ull) == 0ull) {
                        uint32_t t0 = (uint32_t)(chW >> (j1 & 63u));
                        uint32_t t1 = (uint32_t)(chWh >> (j1 & 63u));
                        uint32_t bit = (j1 < 64u) ? t0 : t1;
                        unsigned long long m1 = __ballot((bit & 1u) == 0u);
                        uint32_t js;
                        if (m1 != 0ull) {
                            int k = __ffsll(m1) - 1;
                            js = ((uint32_t)__builtin_amdgcn_readlane((int)Pc, k)) & 0xFFFFu;
                        } else {
                            uint32_t j2 = Pc >> 16;
                            uint32_t u0 = (uint32_t)(chW >> (j2 & 63u));
                            uint32_t u1 = (uint32_t)(chWh >> (j2 & 63u));
                            uint32_t b2 = (j2 < 64u) ? u0 : u1;
                            unsigned long long m2 = __ballot((b2 & 1u) == 0u) & 0x1FFFFFFFFull;
                            int k = __ffsll(m2) - 1;
                            js = ((uint32_t)__builtin_amdgcn_readlane((int)Pc, k)) >> 16;
                        }
                        if (js < 96u) {
                            if (js < 64u) chW |= 1ull << js; else chWh |= 1ull << (js & 63u);
                        }
                        uint32_t cell = js * (uint32_t)NP1 + (uint32_t)aa;
                        cv = (t == (uint32_t)rr) ? cell : cv;
                    }
                }
                Pc = Pn;
                j1 = Pn & 0xFFFFu;
            }
        };
        SEG(ov0, c0, 0);
        SEG(ov1, c1, 64);
        SEG(ov2, c2, 128);
        s_match[t] = c0; s_match[64 + t] = c1; s_match[128 + t] = c2;
    } else {
        // waves 1-3: zero-fill output concurrently with wave 0's loop
        for (int i = t - 64; i < 2352; i += 192)
            ((float4*)out)[i] = make_float4(0.f, 0.f, 0.f, 0.f);
        if (t == 64) out[9408] = 0.f;
    }
    __syncthreads();
    if (t < NAG) {
        uint32_t c = s_match[t];
        if (c != 0xFFFFFFFFu) out[c] = 1.0f;
    }
}

extern "C" void kernel_launch(void* const* d_in, const int* in_sizes, int n_in,
                              void* d_out, int out_size, void* d_ws, size_t ws_size,
                              hipStream_t stream) {
    const float* W = (const float*)d_in[0];
    const float* F = (const float*)d_in[1];
    const float* R = (const float*)d_in[2];
    float* out = (float*)d_out;

    uint32_t* packed = (uint32_t*)d_ws;                      // NAG*64 u32 = 48 KiB
    short* ord = (short*)((char*)d_ws + NAG * 64 * 4);       // 192 shorts
    short* td  = (short*)((char*)d_ws + NAG * 64 * 4 + NAG * 2);  // 192 shorts

    decode_kernel<<<2 * WB + RB, 256, 0, stream>>>(W, F, R, (short*)packed, ord, td);
    sd_kernel<<<1, 256, 0, stream>>>(packed, ord, td, out);
}